// Round 7
// baseline (431.067 us; speedup 1.0000x reference)
//
#include <hip/hip_runtime.h>
#include <hip/hip_bf16.h>
#include <cstddef>

// Fused 3-layer LSTM, wavefront-pipelined, swapped-operand MFMA, 16 waves.
// Block = 16 batches, 1024 threads = 16 waves, all <=128 VGPR -> 4 waves/SIMD.
// Roles (spread so wid%4 balances SIMDs):
//   L0: wid 0,5,10 (NT=4 tiles each, tiles 0-11, KS=2)
//   L1: wid 4,12,1,6,14,3 (NT=2, tiles 0-11, KS=4)   [writes boundary -> A2]
//   L2: wid 8,9,13,2,7,11 (NT=2, tiles 0-11, KS=4)   [wid 2 also stages x]
//   orphan: wid 15 (tile 12 of L0, L1, L2)
// Skew: iter it -> L0@t=it, L1@t=it-1, L2@t=it-2. One s_barrier per iter.
// Swapped MFMA: acc = mfma(W_frag, act_frag); lane (b=lane&15,kg=lane>>4)
// holds gates i,f,g,o of unit n=(T0+q)*4+kg, batch b -> in-register update.
// Act LDS fragment-major: addr(k,b) = (k>>3)*128 + b*8 + (k&7) shorts.
// Bias rides act==1.0 column: L0 k=58, L1/L2 k=100.

#define T_STEPS 256
#define BTOT    4096
#define NTHR    1024

typedef __attribute__((ext_vector_type(8))) short short8;
typedef __attribute__((ext_vector_type(4))) float f32x4;

#define BAR() do { \
    asm volatile("s_waitcnt lgkmcnt(0)" ::: "memory"); \
    __builtin_amdgcn_sched_barrier(0); \
    __builtin_amdgcn_s_barrier(); \
    __builtin_amdgcn_sched_barrier(0); \
} while (0)

__device__ __forceinline__ float fast_sigmoid(float x) {
    float e = __builtin_amdgcn_exp2f(-1.4426950408889634f * x);
    return __builtin_amdgcn_rcpf(1.0f + e);
}
__device__ __forceinline__ float fast_tanh(float x) {
    float e = __builtin_amdgcn_exp2f(2.8853900817779268f * x);
    return 1.0f - 2.0f * __builtin_amdgcn_rcpf(1.0f + e);
}
__device__ __forceinline__ unsigned short f2bf(float x) {
    union { __hip_bfloat16 b; unsigned short s; } u;
    u.b = __float2bfloat16(x);
    return u.s;
}
__device__ __forceinline__ float bf2f(unsigned short s) {
    union { unsigned u; float f; } v; v.u = (unsigned)s << 16; return v.f;
}
// Dekker trunc split: returns (hi_bits<<16) | lo_bits; hi exact-truncated,
// lo = v - hi exact in fp32, then truncated. |err| <= 2^-14 |v|.
__device__ __forceinline__ unsigned split2(float v) {
    union { float f; unsigned u; } x; x.f = v;
    union { unsigned u; float f; } h; h.u = x.u & 0xFFFF0000u;
    union { float f; unsigned u; } y; y.f = v - h.f;
    return (x.u & 0xFFFF0000u) | (y.u >> 16);
}

// Weights -> (hi,lo) A-side frags, RNE split (prologue only).
// K-packed [w_ih(XK) | w_hh(50) | bias@BIASK]. Row N' = (T0+q)*16 + (lane&15).
template<int NT, int KS, int XK, int BIASK>
__device__ __forceinline__ void load_wb(int T0, int lane,
    const float* __restrict__ w_ih, const float* __restrict__ w_hh,
    const float* __restrict__ b_ih, const float* __restrict__ b_hh,
    short8 (&Wh)[NT][KS], short8 (&Wl)[NT][KS])
{
    const int m = lane & 15, kg = lane >> 4;
    #pragma unroll
    for (int q = 0; q < NT; ++q) {
        int gp = (T0 + q) * 16 + m;                      // N' = 4n+g
        int gr = (gp < 200) ? ((gp & 3) * 50 + (gp >> 2)) : -1;
        #pragma unroll
        for (int ks = 0; ks < KS; ++ks)
            #pragma unroll
            for (int e = 0; e < 8; ++e) {
                int k = ks * 32 + kg * 8 + e;
                float v = 0.0f;
                if (gr >= 0) {
                    if (k < XK) v = w_ih[gr * XK + k];
                    else if (k < XK + 50) v = w_hh[gr * 50 + (k - XK)];
                    else if (k == BIASK) v = b_ih[gr] + b_hh[gr];
                }
                unsigned short hb = f2bf(v);
                Wh[q][ks][e] = (short)hb;
                Wl[q][ks][e] = (short)f2bf(v - bf2f(hb));
            }
    }
}

// One layer-step: per-ks frag read + 3-term MFMA (2 A-frags live),
// in-register cell update, trunc-split h writes.
template<int NT, int KS, int HK, bool WRB, bool LASTL>
__device__ __forceinline__ void step_body(
    int t, int T0, int lane,
    const short* Arh, const short* Arl,      // act read buf
    short* Awh, short* Awl,                  // own act write buf (h at HK+n)
    short* Axh, short* Axl,                  // boundary buf (k=n), if WRB
    float* hfp,
    const short8 (&Wh)[NT][KS], const short8 (&Wl)[NT][KS],
    float (&cst)[NT])
{
    const int b = lane & 15, kg = lane >> 4;

    f32x4 acc[NT];
    #pragma unroll
    for (int q = 0; q < NT; ++q) acc[q] = (f32x4){0.0f, 0.0f, 0.0f, 0.0f};

    #pragma unroll
    for (int ks = 0; ks < KS; ++ks) {
        int ga = (ks * 4 + kg) * 128 + b * 8;
        short8 Ah = *(const short8*)&Arh[ga];
        short8 Al = *(const short8*)&Arl[ga];
        #pragma unroll
        for (int q = 0; q < NT; ++q)
            acc[q] = __builtin_amdgcn_mfma_f32_16x16x32_bf16(Wh[q][ks], Ah, acc[q], 0, 0, 0);
        #pragma unroll
        for (int q = 0; q < NT; ++q)
            acc[q] = __builtin_amdgcn_mfma_f32_16x16x32_bf16(Wl[q][ks], Ah, acc[q], 0, 0, 0);
        #pragma unroll
        for (int q = 0; q < NT; ++q)
            acc[q] = __builtin_amdgcn_mfma_f32_16x16x32_bf16(Wh[q][ks], Al, acc[q], 0, 0, 0);
    }

    #pragma unroll
    for (int q = 0; q < NT; ++q) {
        int n = (T0 + q) * 4 + kg;
        if (n < 50) {
            float ig = fast_sigmoid(acc[q][0]);
            float fg = fast_sigmoid(acc[q][1]);
            float gg = fast_tanh(acc[q][2]);
            float og = fast_sigmoid(acc[q][3]);
            float c  = fmaf(fg, cst[q], ig * gg);
            cst[q] = c;
            float h = og * fast_tanh(c);
            unsigned p = split2(h);
            int k  = HK + n;
            int ad = (k >> 3) * 128 + b * 8 + (k & 7);
            Awh[ad] = (short)(p >> 16);
            Awl[ad] = (short)p;
            if (WRB) {
                int ad2 = (n >> 3) * 128 + b * 8 + (n & 7);
                Axh[ad2] = (short)(p >> 16);
                Axl[ad2] = (short)p;
            }
            if (LASTL && t == T_STEPS - 1) hfp[b * 56 + n] = h;
        }
    }
}

template<int NT>
__device__ void role_l0(int T0, int lane,
    const float* w_ih, const float* w_hh, const float* b_ih, const float* b_hh,
    short (*A0h)[1024], short (*A0l)[1024],
    short (*A1h)[2048], short (*A1l)[2048])
{
    short8 Wh[NT][2], Wl[NT][2];
    load_wb<NT, 2, 8, 58>(T0, lane, w_ih, w_hh, b_ih, b_hh, Wh, Wl);
    float cst[NT];
    #pragma unroll
    for (int q = 0; q < NT; ++q) cst[q] = 0.0f;

    for (int it = 0; it < T_STEPS + 2; ++it) {
        if (it < T_STEPS) {
            int cur = it & 1, nxt = cur ^ 1;
            step_body<NT, 2, 8, true, false>(it, T0, lane,
                A0h[cur], A0l[cur], A0h[nxt], A0l[nxt],
                A1h[cur], A1l[cur], nullptr, Wh, Wl, cst);
        }
        BAR();
    }
}

// Mid-layer wave, NT=2 tiles. LASTL: L2 (skew 2, writes hf at t=255);
// else L1 (skew 1, writes boundary to A2). XST: also stages x -> A0.
template<bool LASTL, bool XST>
__device__ void role_mid(int T0, int lane, int b0, const float* __restrict__ xf,
    const float* w_ih, const float* w_hh, const float* b_ih, const float* b_hh,
    short (*Arh)[2048], short (*Arl)[2048],
    short (*Axh)[2048], short (*Axl)[2048],
    short (*A0h)[1024], short (*A0l)[1024],
    float* hfp)
{
    constexpr int SKEW = LASTL ? 2 : 1;
    short8 Wh[2][4], Wl[2][4];
    load_wb<2, 4, 50, 100>(T0, lane, w_ih, w_hh, b_ih, b_hh, Wh, Wl);
    float cst[2] = {0.0f, 0.0f};
    const int bb = lane & 15, kg = lane >> 4;

    for (int it = 0; it < T_STEPS + 2; ++it) {
        const bool stg = XST && (kg == 0) && (it + 1 < T_STEPS);
        float xs[8];
        if (stg) {
            const float* xr = &xf[((size_t)(b0 + bb) * T_STEPS + (it + 1)) * 8];
            *(float4*)&xs[0] = *(const float4*)xr;
            *(float4*)&xs[4] = *(const float4*)(xr + 4);
        }
        int t = it - SKEW;
        if (t >= 0 && t < T_STEPS) {
            step_body<2, 4, 50, !LASTL, LASTL>(t, T0, lane,
                Arh[t & 1], Arl[t & 1], Arh[(t + 1) & 1], Arl[(t + 1) & 1],
                LASTL ? (short*)nullptr : Axh[t & 1],
                LASTL ? (short*)nullptr : Axl[t & 1],
                hfp, Wh, Wl, cst);
        }
        if (stg) {
            int nb = (it + 1) & 1;
            short8 hi, lo;
            #pragma unroll
            for (int e = 0; e < 8; ++e) {
                unsigned p = split2(xs[e]);
                hi[e] = (short)(p >> 16);
                lo[e] = (short)p;
            }
            *(short8*)&A0h[nb][bb * 8] = hi;
            *(short8*)&A0l[nb][bb * 8] = lo;
        }
        BAR();
    }
}

// Orphan: tile 12 of L0, L1, L2 (skews 0,1,2).
__device__ void role_orphan(int lane,
    const float* w_ih0, const float* w_hh0, const float* b_ih0, const float* b_hh0,
    const float* w_ih1, const float* w_hh1, const float* b_ih1, const float* b_hh1,
    const float* w_ih2, const float* w_hh2, const float* b_ih2, const float* b_hh2,
    short (*A0h)[1024], short (*A0l)[1024],
    short (*A1h)[2048], short (*A1l)[2048],
    short (*A2h)[2048], short (*A2l)[2048],
    float* hfp)
{
    short8 W0h[1][2], W0l[1][2], W1h[1][4], W1l[1][4], W2h[1][4], W2l[1][4];
    load_wb<1, 2, 8, 58>(12, lane, w_ih0, w_hh0, b_ih0, b_hh0, W0h, W0l);
    load_wb<1, 4, 50, 100>(12, lane, w_ih1, w_hh1, b_ih1, b_hh1, W1h, W1l);
    load_wb<1, 4, 50, 100>(12, lane, w_ih2, w_hh2, b_ih2, b_hh2, W2h, W2l);
    float c0[1] = {0.0f}, c1[1] = {0.0f}, c2[1] = {0.0f};

    for (int it = 0; it < T_STEPS + 2; ++it) {
        if (it < T_STEPS)
            step_body<1, 2, 8, true, false>(it, 12, lane,
                A0h[it & 1], A0l[it & 1], A0h[(it + 1) & 1], A0l[(it + 1) & 1],
                A1h[it & 1], A1l[it & 1], nullptr, W0h, W0l, c0);
        int t1 = it - 1;
        if (t1 >= 0 && t1 < T_STEPS)
            step_body<1, 4, 50, true, false>(t1, 12, lane,
                A1h[t1 & 1], A1l[t1 & 1], A1h[(t1 + 1) & 1], A1l[(t1 + 1) & 1],
                A2h[t1 & 1], A2l[t1 & 1], nullptr, W1h, W1l, c1);
        int t2 = it - 2;
        if (t2 >= 0 && t2 < T_STEPS)
            step_body<1, 4, 50, false, true>(t2, 12, lane,
                A2h[t2 & 1], A2l[t2 & 1], A2h[(t2 + 1) & 1], A2l[(t2 + 1) & 1],
                nullptr, nullptr, hfp, W2h, W2l, c2);
        BAR();
    }
}

__global__ __launch_bounds__(NTHR, 4) void lstm_fused(
    const float* __restrict__ xf,
    const float* w_ih0, const float* w_hh0, const float* b_ih0, const float* b_hh0,
    const float* w_ih1, const float* w_hh1, const float* b_ih1, const float* b_hh1,
    const float* w_ih2, const float* w_hh2, const float* b_ih2, const float* b_hh2,
    const float* __restrict__ w_fc, const float* __restrict__ b_fc,
    float* __restrict__ out)
{
    __shared__ __align__(16) short A0h[2][1024], A0l[2][1024];   // L0 act (K=64)
    __shared__ __align__(16) short A1h[2][2048], A1l[2][2048];   // L1 act (K=128)
    __shared__ __align__(16) short A2h[2][2048], A2l[2][2048];   // L2 act (K=128)
    __shared__ __align__(16) float hf[16 * 56];

    const int tid  = threadIdx.x;
    const int lane = tid & 63;
    const int wid  = tid >> 6;
    const int b0   = blockIdx.x * 16;

    for (int i = tid; i < 2048; i += NTHR) { ((short*)A0h)[i] = 0; ((short*)A0l)[i] = 0; }
    for (int i = tid; i < 4096; i += NTHR) {
        ((short*)A1h)[i] = 0; ((short*)A1l)[i] = 0;
        ((short*)A2h)[i] = 0; ((short*)A2l)[i] = 0;
    }
    __syncthreads();

    // bias act columns = 1.0 (both bufs); x(0) -> A0 buf0
    if (tid < 32) {
        int buf = tid >> 4, b = tid & 15;
        A0h[buf][(58 >> 3) * 128 + b * 8 + (58 & 7)] = (short)0x3F80;
        A1h[buf][(100 >> 3) * 128 + b * 8 + (100 & 7)] = (short)0x3F80;
        A2h[buf][(100 >> 3) * 128 + b * 8 + (100 & 7)] = (short)0x3F80;
    }
    if (tid < 16) {
        int b = tid;
        #pragma unroll
        for (int j = 0; j < 8; ++j) {
            float v = xf[((size_t)(b0 + b) * T_STEPS + 0) * 8 + j];
            unsigned p = split2(v);
            A0h[0][b * 8 + j] = (short)(p >> 16);
            A0l[0][b * 8 + j] = (short)p;
        }
    }
    __syncthreads();

    // Role table: L0 at wid 0,5,10; orphan 15; L1/L2 mids fill, balanced mod 4.
    if      (wid == 0)  role_l0<4>(0, lane, w_ih0, w_hh0, b_ih0, b_hh0, A0h, A0l, A1h, A1l);
    else if (wid == 5)  role_l0<4>(4, lane, w_ih0, w_hh0, b_ih0, b_hh0, A0h, A0l, A1h, A1l);
    else if (wid == 10) role_l0<4>(8, lane, w_ih0, w_hh0, b_ih0, b_hh0, A0h, A0l, A1h, A1l);
    else if (wid == 4)  role_mid<false, false>(0,  lane, b0, xf, w_ih1, w_hh1, b_ih1, b_hh1, A1h, A1l, A2h, A2l, A0h, A0l, nullptr);
    else if (wid == 12) role_mid<false, false>(2,  lane, b0, xf, w_ih1, w_hh1, b_ih1, b_hh1, A1h, A1l, A2h, A2l, A0h, A0l, nullptr);
    else if (wid == 1)  role_mid<false, false>(4,  lane, b0, xf, w_ih1, w_hh1, b_ih1, b_hh1, A1h, A1l, A2h, A2l, A0h, A0l, nullptr);
    else if (wid == 6)  role_mid<false, false>(6,  lane, b0, xf, w_ih1, w_hh1, b_ih1, b_hh1, A1h, A1l, A2h, A2l, A0h, A0l, nullptr);
    else if (wid == 14) role_mid<false, false>(8,  lane, b0, xf, w_ih1, w_hh1, b_ih1, b_hh1, A1h, A1l, A2h, A2l, A0h, A0l, nullptr);
    else if (wid == 3)  role_mid<false, false>(10, lane, b0, xf, w_ih1, w_hh1, b_ih1, b_hh1, A1h, A1l, A2h, A2l, A0h, A0l, nullptr);
    else if (wid == 8)  role_mid<true,  false>(0,  lane, b0, xf, w_ih2, w_hh2, b_ih2, b_hh2, A2h, A2l, nullptr, nullptr, A0h, A0l, hf);
    else if (wid == 9)  role_mid<true,  false>(2,  lane, b0, xf, w_ih2, w_hh2, b_ih2, b_hh2, A2h, A2l, nullptr, nullptr, A0h, A0l, hf);
    else if (wid == 13) role_mid<true,  false>(4,  lane, b0, xf, w_ih2, w_hh2, b_ih2, b_hh2, A2h, A2l, nullptr, nullptr, A0h, A0l, hf);
    else if (wid == 2)  role_mid<true,  true >(6,  lane, b0, xf, w_ih2, w_hh2, b_ih2, b_hh2, A2h, A2l, nullptr, nullptr, A0h, A0l, hf);
    else if (wid == 7)  role_mid<true,  false>(8,  lane, b0, xf, w_ih2, w_hh2, b_ih2, b_hh2, A2h, A2l, nullptr, nullptr, A0h, A0l, hf);
    else if (wid == 11) role_mid<true,  false>(10, lane, b0, xf, w_ih2, w_hh2, b_ih2, b_hh2, A2h, A2l, nullptr, nullptr, A0h, A0l, hf);
    else                role_orphan(lane,
                            w_ih0, w_hh0, b_ih0, b_hh0,
                            w_ih1, w_hh1, b_ih1, b_hh1,
                            w_ih2, w_hh2, b_ih2, b_hh2,
                            A0h, A0l, A1h, A1l, A2h, A2l, hf);

    __syncthreads();

    if (tid < 96) {
        int b = tid / 6, o = tid - b * 6;
        float a = b_fc[o];
        #pragma unroll
        for (int n = 0; n < 50; ++n)
            a = fmaf(w_fc[o * 50 + n], hf[b * 56 + n], a);
        out[(size_t)(b0 + b) * 6 + o] = a;
    }
}

extern "C" void kernel_launch(void* const* d_in, const int* in_sizes, int n_in,
                              void* d_out, int out_size, void* d_ws, size_t ws_size,
                              hipStream_t stream) {
    (void)in_sizes; (void)n_in; (void)d_ws; (void)ws_size; (void)out_size;

    const float* x     = (const float*)d_in[0];
    const float* w_ih0 = (const float*)d_in[1];
    const float* w_hh0 = (const float*)d_in[2];
    const float* b_ih0 = (const float*)d_in[3];
    const float* b_hh0 = (const float*)d_in[4];
    const float* w_ih1 = (const float*)d_in[5];
    const float* w_hh1 = (const float*)d_in[6];
    const float* b_ih1 = (const float*)d_in[7];
    const float* b_hh1 = (const float*)d_in[8];
    const float* w_ih2 = (const float*)d_in[9];
    const float* w_hh2 = (const float*)d_in[10];
    const float* b_ih2 = (const float*)d_in[11];
    const float* b_hh2 = (const float*)d_in[12];
    const float* w_fc  = (const float*)d_in[13];
    const float* b_fc  = (const float*)d_in[14];
    float* out = (float*)d_out;

    lstm_fused<<<dim3(BTOT / 16), dim3(NTHR), 0, stream>>>(
        x, w_ih0, w_hh0, b_ih0, b_hh0, w_ih1, w_hh1, b_ih1, b_hh1,
        w_ih2, w_hh2, b_ih2, b_hh2, w_fc, b_fc, out);
}